// Round 6
// baseline (321.064 us; speedup 1.0000x reference)
//
#include <hip/hip_runtime.h>
#include <math.h>

#define N_NODES 50000
#define N_EDGES 800000
#define ETOT    (N_EDGES + N_NODES)
#define EPAD_MAX 1200000
#define IN_CH   128
#define OUT_CH  40
#define NEG     0.2f
#define CAP     64         // max cached slots per node (Poisson(17) max ~48)

// single-level bucketed CSR
#define NPF   98           // nodes per fine partition
#define NFINE 512          // 512*98 = 50176 >= 50000
#define FCAP  2400         // capacity per fine (mean ~1666)

#define MBLK  ((N_NODES + 127) / 128)   // 391 row-blocks for the GEMMs

typedef __attribute__((ext_vector_type(8))) short bf16x8;
typedef __attribute__((ext_vector_type(4))) float f32x4;
typedef __attribute__((ext_vector_type(2))) float f32x2;

__device__ inline unsigned short f2bf(float f) {
    unsigned int u = __float_as_uint(f);
    return (unsigned short)((u + 0x7FFFu + ((u >> 16) & 1u)) >> 16);
}
__device__ inline float bf2f(unsigned short u) {
    return __uint_as_float((unsigned int)u << 16);
}
__device__ inline float lrelu(float a) { return (a > 0.f) ? a : NEG * a; }

__device__ inline bf16x8 u4_to_bf(uint4 v) {
    union { uint4 u; bf16x8 b; } c; c.u = v; return c.b;
}

// ---------------------------------------------------------------------------
// W1 transpose (tiny, runs before the combined kernel).
// ---------------------------------------------------------------------------
__global__ __launch_bounds__(256) void k_wt1(const float* __restrict__ W1,
                                             unsigned short* __restrict__ Wt1) {
    int i = blockIdx.x * 256 + threadIdx.x;      // 32768 = 128 blocks
    int n = i >> 7, k = i & 127;
    Wt1[i] = f2bf(W1[(long)k * 256 + n]);
}

// ---------------------------------------------------------------------------
// Barrier-free register GEMM with fused attention logits.
// K<=256: per-K-step operand slices are L1-resident (A 8KB + B 8KB), so lanes
// load MFMA fragments DIRECTLY from global (no LDS, no __syncthreads, no
// staging VALU). 4 quads share each 64B line -> L1 serves 3/4. Accumulation
// order identical to the staged version (same k0 loop) -> bit-identical C.
// ---------------------------------------------------------------------------
template<int BN, int FM, int FN, bool CVT, bool FP8OUT, bool L4>
__device__ __forceinline__ void mfma_body(int bx, int by,
                                          const void* __restrict__ Araw,
                                          const unsigned short* __restrict__ Bt,
                                          void* __restrict__ Cout,
                                          const float* __restrict__ a_s,
                                          const float* __restrict__ a_d,
                                          float* __restrict__ als,
                                          float* __restrict__ ald,
                                          int M, int K, int Ncol) {
    const int WCOLS = BN / (FN * 16);
    int tid = threadIdx.x;
    int wave = tid >> 6, lane = tid & 63;
    int quad = lane >> 4, l16 = lane & 15;
    int wr = wave / WCOLS, wc = wave % WCOLS;
    long row0 = (long)bx * 128;
    int col0 = by * BN;

    f32x4 acc[FM][FN] = {};

    for (int k0 = 0; k0 < K; k0 += 32) {
        bf16x8 af[FM], bfr[FN];
        #pragma unroll
        for (int i = 0; i < FM; ++i) {
            long row = row0 + wr * (FM * 16) + i * 16 + l16;
            bool ok = (row < M);
            if (CVT) {
                const float* ap = (const float*)Araw + row * K + k0 + quad * 8;
                float4 v0 = {0.f,0.f,0.f,0.f}, v1 = {0.f,0.f,0.f,0.f};
                if (ok) { v0 = *(const float4*)ap; v1 = *(const float4*)(ap + 4); }
                bf16x8 a;
                a[0] = (short)f2bf(v0.x); a[1] = (short)f2bf(v0.y);
                a[2] = (short)f2bf(v0.z); a[3] = (short)f2bf(v0.w);
                a[4] = (short)f2bf(v1.x); a[5] = (short)f2bf(v1.y);
                a[6] = (short)f2bf(v1.z); a[7] = (short)f2bf(v1.w);
                af[i] = a;
            } else {
                uint4 v = {0u,0u,0u,0u};
                if (ok) v = *(const uint4*)((const unsigned short*)Araw + row * K + k0 + quad * 8);
                af[i] = u4_to_bf(v);
            }
        }
        #pragma unroll
        for (int j = 0; j < FN; ++j) {
            int col = col0 + wc * (FN * 16) + j * 16 + l16;
            bfr[j] = u4_to_bf(*(const uint4*)(Bt + (long)col * K + k0 + quad * 8));
        }
        #pragma unroll
        for (int i = 0; i < FM; ++i)
            #pragma unroll
            for (int j = 0; j < FN; ++j)
                acc[i][j] = __builtin_amdgcn_mfma_f32_16x16x32_bf16(af[i], bfr[j], acc[i][j], 0, 0, 0);
    }

    // fused logits
    {
        int head = L4 ? (by * WCOLS + wc) : 0;
        float as_v[FN], ad_v[FN];
        #pragma unroll
        for (int j = 0; j < FN; ++j) {
            int cidx = j * 16 + l16;
            if (L4) {
                as_v[j] = a_s[head * 64 + cidx];
                ad_v[j] = a_d[head * 64 + cidx];
            } else {
                as_v[j] = (cidx < OUT_CH) ? a_s[cidx] : 0.f;
                ad_v[j] = (cidx < OUT_CH) ? a_d[cidx] : 0.f;
            }
        }
        #pragma unroll
        for (int i = 0; i < FM; ++i) {
            #pragma unroll
            for (int v = 0; v < 4; ++v) {
                float ps = acc[i][0][v] * as_v[0] + acc[i][1][v] * as_v[1]
                         + acc[i][2][v] * as_v[2] + acc[i][3][v] * as_v[3];
                float pd = acc[i][0][v] * ad_v[0] + acc[i][1][v] * ad_v[1]
                         + acc[i][2][v] * ad_v[2] + acc[i][3][v] * ad_v[3];
                #pragma unroll
                for (int off = 1; off < 16; off <<= 1) {
                    ps += __shfl_xor(ps, off);
                    pd += __shfl_xor(pd, off);
                }
                if (l16 == 0) {
                    long row = row0 + wr * (FM * 16) + i * 16 + quad * 4 + v;
                    if (row < M) {
                        if (L4) { als[row * 4 + head] = ps; ald[row * 4 + head] = pd; }
                        else    { als[row] = ps; ald[row] = pd; }
                    }
                }
            }
        }
    }

    if (FP8OUT) {
        unsigned char* C8 = (unsigned char*)Cout;
        #pragma unroll
        for (int i = 0; i < FM; ++i) {
            #pragma unroll
            for (int v = 0; v < 4; ++v) {
                long row = row0 + wr * FM * 16 + i * 16 + quad * 4 + v;
                if (row < M) {
                    int p01 = __builtin_amdgcn_cvt_pk_fp8_f32(acc[i][0][v], acc[i][1][v], 0, false);
                    int p23 = __builtin_amdgcn_cvt_pk_fp8_f32(acc[i][2][v], acc[i][3][v], 0, false);
                    unsigned char* b = C8 + row * 256 + col0 + wc * (FN * 16) + l16;
                    b[0]  = (unsigned char)(p01 & 0xFF);
                    b[16] = (unsigned char)((p01 >> 8) & 0xFF);
                    b[32] = (unsigned char)(p23 & 0xFF);
                    b[48] = (unsigned char)((p23 >> 8) & 0xFF);
                }
            }
        }
    } else {
        unsigned short* C = (unsigned short*)Cout;
        #pragma unroll
        for (int i = 0; i < FM; ++i) {
            long rowb = row0 + wr * FM * 16 + i * 16 + quad * 4;
            #pragma unroll
            for (int j = 0; j < FN; ++j) {
                int col = col0 + wc * FN * 16 + j * 16 + l16;
                if (col < Ncol) {
                    #pragma unroll
                    for (int v = 0; v < 4; ++v) {
                        long r = rowb + v;
                        if (r < M) C[r * Ncol + col] = f2bf(acc[i][j][v]);
                    }
                }
            }
        }
    }
}

// Standalone GEMM kernel (layers 2 and 3).
template<int BN, int FM, int FN, bool CVT, bool FP8OUT, bool L4>
__global__ __launch_bounds__(256) void k_mfma(const void* __restrict__ Araw,
                                              const unsigned short* __restrict__ Bt,
                                              void* __restrict__ Cout,
                                              const float* __restrict__ a_s,
                                              const float* __restrict__ a_d,
                                              float* __restrict__ als,
                                              float* __restrict__ ald,
                                              int M, int K, int Ncol) {
    mfma_body<BN, FM, FN, CVT, FP8OUT, L4>(blockIdx.x, blockIdx.y,
                                           Araw, Bt, Cout, a_s, a_d, als, ald, M, K, Ncol);
}

// ---------------------------------------------------------------------------
// Combined front kernel: edge bucketing (blocks [0,256)) + W2/W3 transposes
// ([256,576)) + layer-1 GEMM ([576, 576+2*MBLK)). GEMM path is now LDS-free,
// so kernel LDS = bucketing's 6KB only.
// ---------------------------------------------------------------------------
__global__ __launch_bounds__(256) void k_front(const int* __restrict__ ei,
                                               int* __restrict__ fcur,
                                               unsigned int* __restrict__ fbuf,
                                               const float* __restrict__ W2,
                                               const float* __restrict__ W3,
                                               unsigned short* __restrict__ Wt2,
                                               unsigned short* __restrict__ Wt3,
                                               const float* __restrict__ x,
                                               const unsigned short* __restrict__ Wt1,
                                               unsigned char* __restrict__ hA8,
                                               const float* __restrict__ as1,
                                               const float* __restrict__ ad1,
                                               float* __restrict__ als,
                                               float* __restrict__ ald) {
    int b = blockIdx.x;
    if (b >= 576) {
        int g = b - 576;
        mfma_body<128, 4, 4, true, true, true>(g % MBLK, g / MBLK,
                                               x, Wt1, hA8, as1, ad1, als, ald,
                                               N_NODES, IN_CH, 256);
        return;
    }
    if (b >= 256) {
        int j = (b - 256) * 256 + threadIdx.x;
        if (j < 65536) {                       // W2: 256 x 256
            int n = j >> 8, k = j & 255;
            Wt2[j] = f2bf(W2[(long)k * 256 + n]);
        } else {                               // W3: 64(pad) x 256
            int jj = j - 65536;                // < 16384
            int n = jj >> 8, k = jj & 255;
            Wt3[jj] = (n < OUT_CH) ? f2bf(W3[(long)k * OUT_CH + n]) : (unsigned short)0;
        }
        return;
    }
    // ---- edge bucketing ----
    __shared__ int lcnt[NFINE], lbase[NFINE], lcur[NFINE];
    int tid = threadIdx.x;
    for (int i = tid; i < NFINE; i += 256) lcnt[i] = 0;
    __syncthreads();
    for (int i = b * 256 + tid; i < ETOT; i += 256 * 256) {
        int d = (i < N_EDGES) ? ei[N_EDGES + i] : (i - N_EDGES);
        atomicAdd(&lcnt[d / NPF], 1);
    }
    __syncthreads();
    for (int i = tid; i < NFINE; i += 256) {
        lbase[i] = atomicAdd(&fcur[i], lcnt[i]);
        lcur[i] = 0;
    }
    __syncthreads();
    for (int i = b * 256 + tid; i < ETOT; i += 256 * 256) {
        int s, d;
        if (i < N_EDGES) { s = ei[i]; d = ei[N_EDGES + i]; }
        else             { s = i - N_EDGES; d = s; }
        int p = d / NPF;
        int off = atomicAdd(&lcur[p], 1);
        fbuf[(long)p * FCAP + lbase[p] + off] = (unsigned int)s | ((unsigned int)d << 16);
    }
}

// ---------------------------------------------------------------------------
// Merged CSR finalize: count + per-partition scan + global atomic base +
// scatter + pad fill (pad-8, matching the proven aggregation kernels).
// ---------------------------------------------------------------------------
__global__ __launch_bounds__(256) void k_build(const int* __restrict__ fcur,
                                               const unsigned int* __restrict__ fbuf,
                                               int* __restrict__ deg,
                                               int* __restrict__ gcur,
                                               int* __restrict__ start,
                                               int* __restrict__ eSrc) {
    __shared__ int cnt[NPF];
    __shared__ int sval[128];
    __shared__ int offs[NPF];
    __shared__ int base_[NPF];
    __shared__ int pbase;
    int f = blockIdx.x;
    int tid = threadIdx.x;
    int n0 = f * NPF;
    int nend = min(n0 + NPF, N_NODES);
    int nn = nend - n0;
    if (tid < NPF) cnt[tid] = 0;
    __syncthreads();
    int n = fcur[f];
    for (int i = tid; i < n; i += 256)
        atomicAdd(&cnt[(int)(fbuf[(long)f * FCAP + i] >> 16) - n0], 1);
    __syncthreads();
    int pd = 0;
    if (tid < 128) {
        pd = (tid < nn) ? ((cnt[tid] + 7) & ~7) : 0;   // pad-8
        sval[tid] = pd;
    }
    __syncthreads();
    #pragma unroll
    for (int off = 1; off < 128; off <<= 1) {
        int t = 0;
        if (tid < 128 && tid >= off) t = sval[tid - off];
        __syncthreads();
        if (tid < 128) sval[tid] += t;
        __syncthreads();
    }
    if (tid == 0) pbase = atomicAdd(gcur, sval[127]);  // partition base, order-free
    __syncthreads();
    if (tid < nn) {
        int st = pbase + sval[tid] - pd;               // exclusive
        deg[n0 + tid] = cnt[tid];
        start[n0 + tid] = st;
        offs[tid] = st;
        base_[tid] = st;
    }
    __syncthreads();
    for (int i = tid; i < n; i += 256) {
        unsigned int u = fbuf[(long)f * FCAP + i];
        int d = (int)(u >> 16);
        int pos = atomicAdd(&offs[d - n0], 1);
        eSrc[pos] = (int)(u & 0xFFFFu);
    }
    __syncthreads();
    if (tid < nn) {
        int endp = offs[tid];
        int dg = endp - base_[tid];
        int stop = base_[tid] + ((dg + 7) & ~7);
        for (int k2 = endp; k2 < stop; ++k2) eSrc[k2] = -1;
    }
}

// ---------------------------------------------------------------------------
// Aggregation (4-head): quarter-wave per edge (16 lanes x uint4 = 256B/row),
// 16 ch/lane, split sbuf/wbuf LDS (conflict-free). At the gather-serve floor
// (~44.5us) — three structures all pin here; do not restructure further.
// ---------------------------------------------------------------------------
__global__ __launch_bounds__(256) void k_agg4(const unsigned char* __restrict__ h8,
                                              const int* __restrict__ start,
                                              const int* __restrict__ deg,
                                              const int* __restrict__ eSrc,
                                              const float* __restrict__ als,
                                              const float* __restrict__ ald,
                                              const float* __restrict__ bias,
                                              unsigned short* __restrict__ out) {
    __shared__ float wbuf[4][CAP * 4];
    __shared__ int   sbuf[4][CAP];       // pre-scaled src byte offset (ss<<8)
    int wid = threadIdx.x >> 6;
    int node = (blockIdx.x * blockDim.x + threadIdx.x) >> 6;
    int lane = threadIdx.x & 63;
    if (node >= N_NODES) return;
    int st = start[node];
    int dgp = (deg[node] + 7) & ~7;
    const int* ep = eSrc + st;

    // ---- phase 1: weights into LDS ----
    int l16 = lane & 15, headw = lane >> 4;
    float aldd4 = ald[node * 4 + headw];
    int ncap = (dgp < CAP) ? dgp : CAP;
    for (int c = 0; c < ncap; c += 16) {
        int slot = c + l16;
        bool ok = (slot < ncap);
        int raw = ok ? ep[slot] : -1;
        int ss = (raw < 0) ? 0 : raw;
        float a = als[(long)ss * 4 + headw] + aldd4;
        float w = (raw < 0) ? 0.f : __expf(lrelu(a));
        if (ok) {
            wbuf[wid][slot * 4 + headw] = w;
            if (headw == 0) sbuf[wid][slot] = ss << 8;
        }
    }

    // ---- phase 2: quarter-wave per edge, 16 ch/lane (fp8 uint4) ----
    int q = lane >> 4;                   // quarter index = edge sub-slot
    int head = l16 >> 2;                 // 4 lanes per head
    const unsigned char* hb = h8 + l16 * 16;
    float den = 0.f;
    f32x2 acc2[8] = {};

    for (int j = 0; j < ncap; j += 8) {
        int  s0 = sbuf[wid][j + q];
        int  s1 = sbuf[wid][j + 4 + q];
        float w0 = wbuf[wid][(j + q) * 4 + head];
        float w1 = wbuf[wid][(j + 4 + q) * 4 + head];
        uint4 h0 = *(const uint4*)(hb + (long)s0);
        uint4 h1 = *(const uint4*)(hb + (long)s1);
        den += w0 + w1;
        f32x2 W0; W0.x = w0; W0.y = w0;
        f32x2 W1; W1.x = w1; W1.y = w1;
        acc2[0] += W0 * __builtin_amdgcn_cvt_pk_f32_fp8((int)h0.x, false);
        acc2[1] += W0 * __builtin_amdgcn_cvt_pk_f32_fp8((int)h0.x, true);
        acc2[2] += W0 * __builtin_amdgcn_cvt_pk_f32_fp8((int)h0.y, false);
        acc2[3] += W0 * __builtin_amdgcn_cvt_pk_f32_fp8((int)h0.y, true);
        acc2[4] += W0 * __builtin_amdgcn_cvt_pk_f32_fp8((int)h0.z, false);
        acc2[5] += W0 * __builtin_amdgcn_cvt_pk_f32_fp8((int)h0.z, true);
        acc2[6] += W0 * __builtin_amdgcn_cvt_pk_f32_fp8((int)h0.w, false);
        acc2[7] += W0 * __builtin_amdgcn_cvt_pk_f32_fp8((int)h0.w, true);
        acc2[0] += W1 * __builtin_amdgcn_cvt_pk_f32_fp8((int)h1.x, false);
        acc2[1] += W1 * __builtin_amdgcn_cvt_pk_f32_fp8((int)h1.x, true);
        acc2[2] += W1 * __builtin_amdgcn_cvt_pk_f32_fp8((int)h1.y, false);
        acc2[3] += W1 * __builtin_amdgcn_cvt_pk_f32_fp8((int)h1.y, true);
        acc2[4] += W1 * __builtin_amdgcn_cvt_pk_f32_fp8((int)h1.z, false);
        acc2[5] += W1 * __builtin_amdgcn_cvt_pk_f32_fp8((int)h1.z, true);
        acc2[6] += W1 * __builtin_amdgcn_cvt_pk_f32_fp8((int)h1.w, false);
        acc2[7] += W1 * __builtin_amdgcn_cvt_pk_f32_fp8((int)h1.w, true);
    }

    if (dgp > ncap) {                    // overflow (deg > 64: ~never)
        float alddq = ald[node * 4 + head];
        for (int j = ncap; j < dgp; j += 4) {
            int raw = ep[j + q];
            int ss = (raw < 0) ? 0 : raw;
            float w = (raw < 0) ? 0.f : __expf(lrelu(als[(long)ss * 4 + head] + alddq));
            uint4 hv = *(const uint4*)(h8 + ((long)ss << 8) + l16 * 16);
            den += w;
            f32x2 W0; W0.x = w; W0.y = w;
            acc2[0] += W0 * __builtin_amdgcn_cvt_pk_f32_fp8((int)hv.x, false);
            acc2[1] += W0 * __builtin_amdgcn_cvt_pk_f32_fp8((int)hv.x, true);
            acc2[2] += W0 * __builtin_amdgcn_cvt_pk_f32_fp8((int)hv.y, false);
            acc2[3] += W0 * __builtin_amdgcn_cvt_pk_f32_fp8((int)hv.y, true);
            acc2[4] += W0 * __builtin_amdgcn_cvt_pk_f32_fp8((int)hv.z, false);
            acc2[5] += W0 * __builtin_amdgcn_cvt_pk_f32_fp8((int)hv.z, true);
            acc2[6] += W0 * __builtin_amdgcn_cvt_pk_f32_fp8((int)hv.w, false);
            acc2[7] += W0 * __builtin_amdgcn_cvt_pk_f32_fp8((int)hv.w, true);
        }
    }

    // reduce across the 4 quarters (lanes with equal l16)
    den += __shfl_xor(den, 16);
    den += __shfl_xor(den, 32);
    #pragma unroll
    for (int c = 0; c < 8; ++c) {
        acc2[c].x += __shfl_xor(acc2[c].x, 16);
        acc2[c].y += __shfl_xor(acc2[c].y, 16);
        acc2[c].x += __shfl_xor(acc2[c].x, 32);
        acc2[c].y += __shfl_xor(acc2[c].y, 32);
    }

    if (q == 0) {
        float inv = 1.f / den;
        int cb = l16 * 16;
        float4 b0 = *(const float4*)(bias + cb);
        float4 b1 = *(const float4*)(bias + cb + 4);
        float4 b2 = *(const float4*)(bias + cb + 8);
        float4 b3 = *(const float4*)(bias + cb + 12);
        float v0  = fmaxf(acc2[0].x * inv + b0.x, 0.f);
        float v1  = fmaxf(acc2[0].y * inv + b0.y, 0.f);
        float v2  = fmaxf(acc2[1].x * inv + b0.z, 0.f);
        float v3  = fmaxf(acc2[1].y * inv + b0.w, 0.f);
        float v4  = fmaxf(acc2[2].x * inv + b1.x, 0.f);
        float v5  = fmaxf(acc2[2].y * inv + b1.y, 0.f);
        float v6  = fmaxf(acc2[3].x * inv + b1.z, 0.f);
        float v7  = fmaxf(acc2[3].y * inv + b1.w, 0.f);
        float v8  = fmaxf(acc2[4].x * inv + b2.x, 0.f);
        float v9  = fmaxf(acc2[4].y * inv + b2.y, 0.f);
        float v10 = fmaxf(acc2[5].x * inv + b2.z, 0.f);
        float v11 = fmaxf(acc2[5].y * inv + b2.w, 0.f);
        float v12 = fmaxf(acc2[6].x * inv + b3.x, 0.f);
        float v13 = fmaxf(acc2[6].y * inv + b3.y, 0.f);
        float v14 = fmaxf(acc2[7].x * inv + b3.z, 0.f);
        float v15 = fmaxf(acc2[7].y * inv + b3.w, 0.f);
        uint4 o0, o1;
        o0.x = (unsigned int)f2bf(v0)  | ((unsigned int)f2bf(v1)  << 16);
        o0.y = (unsigned int)f2bf(v2)  | ((unsigned int)f2bf(v3)  << 16);
        o0.z = (unsigned int)f2bf(v4)  | ((unsigned int)f2bf(v5)  << 16);
        o0.w = (unsigned int)f2bf(v6)  | ((unsigned int)f2bf(v7)  << 16);
        o1.x = (unsigned int)f2bf(v8)  | ((unsigned int)f2bf(v9)  << 16);
        o1.y = (unsigned int)f2bf(v10) | ((unsigned int)f2bf(v11) << 16);
        o1.z = (unsigned int)f2bf(v12) | ((unsigned int)f2bf(v13) << 16);
        o1.w = (unsigned int)f2bf(v14) | ((unsigned int)f2bf(v15) << 16);
        *(uint4*)(out + (long)node * 256 + cb) = o0;
        *(uint4*)(out + (long)node * 256 + cb + 8) = o1;
    }
}

// ---------------------------------------------------------------------------
// Final layer agg (exact proven R14 version, pad-8).
// ---------------------------------------------------------------------------
__global__ __launch_bounds__(256) void k_agg1(const unsigned short* __restrict__ h,
                                              const int* __restrict__ start,
                                              const int* __restrict__ deg,
                                              const int* __restrict__ eSrc,
                                              const float* __restrict__ als,
                                              const float* __restrict__ ald,
                                              const float* __restrict__ bias,
                                              float* __restrict__ out) {
    int node = (blockIdx.x * blockDim.x + threadIdx.x) >> 6;
    int lane = threadIdx.x & 63;
    if (node >= N_NODES) return;
    int q = lane >> 4, r = lane & 15;
    bool act = (r < 10);
    int st = start[node];
    int dgp = (deg[node] + 7) & ~7;
    const int* ep = eSrc + st;
    float aldd = ald[node];

    float den = 0.f;
    float4 acc = {0.f, 0.f, 0.f, 0.f};

    int j = 0;
    for (; j + 16 <= dgp; j += 16) {
        int base = j + q * 4;
        int s[4];
        float w[4];
        #pragma unroll
        for (int u = 0; u < 4; ++u) s[u] = ep[base + u];
        #pragma unroll
        for (int u = 0; u < 4; ++u) {
            int raw = s[u];
            int ss = (raw < 0) ? 0 : raw;
            w[u] = (raw < 0) ? 0.f : __expf(lrelu(als[ss] + aldd));
            s[u] = ss;
        }
        ushort4 hh[4];
        #pragma unroll
        for (int u = 0; u < 4; ++u) {
            ushort4 t = {0, 0, 0, 0};
            if (act) t = *(const ushort4*)(h + (long)s[u] * OUT_CH + r * 4);
            hh[u] = t;
        }
        #pragma unroll
        for (int u = 0; u < 4; ++u) {
            den += w[u];
            acc.x += w[u] * bf2f(hh[u].x);
            acc.y += w[u] * bf2f(hh[u].y);
            acc.z += w[u] * bf2f(hh[u].z);
            acc.w += w[u] * bf2f(hh[u].w);
        }
    }
    if (j < dgp) {
        int base = j + q * 2;
        int s[2];
        float w[2];
        #pragma unroll
        for (int u = 0; u < 2; ++u) s[u] = ep[base + u];
        #pragma unroll
        for (int u = 0; u < 2; ++u) {
            int raw = s[u];
            int ss = (raw < 0) ? 0 : raw;
            w[u] = (raw < 0) ? 0.f : __expf(lrelu(als[ss] + aldd));
            s[u] = ss;
        }
        ushort4 hh[2];
        #pragma unroll
        for (int u = 0; u < 2; ++u) {
            ushort4 t = {0, 0, 0, 0};
            if (act) t = *(const ushort4*)(h + (long)s[u] * OUT_CH + r * 4);
            hh[u] = t;
        }
        #pragma unroll
        for (int u = 0; u < 2; ++u) {
            den += w[u];
            acc.x += w[u] * bf2f(hh[u].x);
            acc.y += w[u] * bf2f(hh[u].y);
            acc.z += w[u] * bf2f(hh[u].z);
            acc.w += w[u] * bf2f(hh[u].w);
        }
    }

    #pragma unroll
    for (int off = 16; off < 64; off <<= 1) {
        acc.x += __shfl_xor(acc.x, off);
        acc.y += __shfl_xor(acc.y, off);
        acc.z += __shfl_xor(acc.z, off);
        acc.w += __shfl_xor(acc.w, off);
        den   += __shfl_xor(den, off);
    }
    float inv = 1.f / den;
    float4 bv = {0.f, 0.f, 0.f, 0.f};
    if (act) bv = *(const float4*)(bias + r * 4);
    float4 v;
    v.x = acc.x * inv + bv.x;
    v.y = acc.y * inv + bv.y;
    v.z = acc.z * inv + bv.z;
    v.w = acc.w * inv + bv.w;
    float mx = act ? fmaxf(fmaxf(v.x, v.y), fmaxf(v.z, v.w)) : -INFINITY;
    #pragma unroll
    for (int off = 1; off < 16; off <<= 1) mx = fmaxf(mx, __shfl_xor(mx, off));
    float sum = act ? (__expf(v.x - mx) + __expf(v.y - mx) + __expf(v.z - mx) + __expf(v.w - mx)) : 0.f;
    #pragma unroll
    for (int off = 1; off < 16; off <<= 1) sum += __shfl_xor(sum, off);
    float lse = mx + logf(sum);
    if (q == 0 && act) {
        float4 o;
        o.x = v.x - lse;
        o.y = v.y - lse;
        o.z = v.z - lse;
        o.w = v.w - lse;
        *(float4*)(out + (long)node * OUT_CH + r * 4) = o;
    }
}

// ---------------------------------------------------------------------------
extern "C" void kernel_launch(void* const* d_in, const int* in_sizes, int n_in,
                              void* d_out, int out_size, void* d_ws, size_t ws_size,
                              hipStream_t stream) {
    (void)in_sizes; (void)n_in; (void)out_size; (void)ws_size;
    const float* x   = (const float*)d_in[0];
    const int*   ei  = (const int*)d_in[1];
    const float* W1  = (const float*)d_in[2];
    const float* as1 = (const float*)d_in[3];
    const float* ad1 = (const float*)d_in[4];
    const float* b1  = (const float*)d_in[5];
    const float* W2  = (const float*)d_in[6];
    const float* as2 = (const float*)d_in[7];
    const float* ad2 = (const float*)d_in[8];
    const float* b2  = (const float*)d_in[9];
    const float* W3  = (const float*)d_in[10];
    const float* as3 = (const float*)d_in[11];
    const float* ad3 = (const float*)d_in[12];
    const float* b3  = (const float*)d_in[13];
    float* out = (float*)d_out;

    char* p = (char*)d_ws;
    auto alloc = [&](size_t b) { char* r = p; p += (b + 255) & ~(size_t)255; return r; };
    int*   deg   = (int*)alloc((size_t)N_NODES * 4);
    int*   start = (int*)alloc((size_t)N_NODES * 4);
    int*   psum  = (int*)alloc((size_t)NFINE * 4);   // psum[0] = global cursor
    int*   fcur  = (int*)alloc((size_t)NFINE * 4);   // adjacent to psum (both 2048B, 256-aligned)
    unsigned int* fbuf = (unsigned int*)alloc((size_t)NFINE * FCAP * 4);
    int*   eSrc  = (int*)alloc((size_t)EPAD_MAX * 4);
    float* als   = (float*)alloc((size_t)N_NODES * 4 * 4);
    float* ald   = (float*)alloc((size_t)N_NODES * 4 * 4);
    unsigned char*  hA8  = (unsigned char*)alloc((size_t)N_NODES * 256);
    unsigned short* hBbf = (unsigned short*)alloc((size_t)N_NODES * 256 * 2);
    unsigned short* h3bf = (unsigned short*)alloc((size_t)N_NODES * OUT_CH * 2);
    unsigned short* Wt1  = (unsigned short*)alloc((size_t)256 * IN_CH * 2);
    unsigned short* Wt2  = (unsigned short*)alloc((size_t)256 * 256 * 2);
    unsigned short* Wt3  = (unsigned short*)alloc((size_t)64 * 256 * 2);

    const int WB = (N_NODES + 3) / 4;

    // ---- front: memset + W1 transpose, then {bucketing || W2/W3 || GEMM1} ----
    hipMemsetAsync(psum, 0, (size_t)NFINE * 8, stream);
    k_wt1<<<128, 256, 0, stream>>>(W1, Wt1);
    k_front<<<576 + 2 * MBLK, 256, 0, stream>>>(ei, fcur, fbuf, W2, W3, Wt2, Wt3,
                                                x, Wt1, hA8, as1, ad1, als, ald);
    k_build<<<NFINE, 256, 0, stream>>>(fcur, fbuf, deg, psum, start, eSrc);

    // ---- layer 1 aggregation ----
    k_agg4<<<WB, 256, 0, stream>>>(hA8, start, deg, eSrc, als, ald, b1, hBbf);

    // ---- layer 2 (bf16 in, fp8 out, fused logits) ----
    k_mfma<128, 4, 4, false, true, true><<<dim3(MBLK, 2), 256, 0, stream>>>(
        hBbf, Wt2, hA8, as2, ad2, als, ald, N_NODES, 256, 256);
    k_agg4<<<WB, 256, 0, stream>>>(hA8, start, deg, eSrc, als, ald, b2, hBbf);

    // ---- layer 3 (bf16 in, bf16 out, fused single-head logits) ----
    k_mfma<64, 2, 4, false, false, false><<<dim3(MBLK, 1), 256, 0, stream>>>(
        hBbf, Wt3, h3bf, as3, ad3, als, ald, N_NODES, 256, OUT_CH);
    k_agg1<<<WB, 256, 0, stream>>>(h3bf, start, deg, eSrc, als, ald, b3, out);
}

// Round 7
// 310.466 us; speedup vs baseline: 1.0341x; 1.0341x over previous
//
#include <hip/hip_runtime.h>
#include <math.h>

#define N_NODES 50000
#define N_EDGES 800000
#define ETOT    (N_EDGES + N_NODES)
#define EPAD_MAX 1200000
#define IN_CH   128
#define OUT_CH  40
#define NEG     0.2f
#define CAP     64         // max cached slots per node (Poisson(17) max ~48)

// single-level bucketed CSR
#define NPF   98           // nodes per fine partition
#define NFINE 512          // 512*98 = 50176 >= 50000
#define FCAP  2400         // capacity per fine (mean ~1666)

#define MBLK  ((N_NODES + 127) / 128)   // 391 row-blocks for the GEMMs

typedef __attribute__((ext_vector_type(8))) short bf16x8;
typedef __attribute__((ext_vector_type(4))) float f32x4;
typedef __attribute__((ext_vector_type(2))) float f32x2;

__device__ inline unsigned short f2bf(float f) {
    unsigned int u = __float_as_uint(f);
    return (unsigned short)((u + 0x7FFFu + ((u >> 16) & 1u)) >> 16);
}
__device__ inline float bf2f(unsigned short u) {
    return __uint_as_float((unsigned int)u << 16);
}
__device__ inline float lrelu(float a) { return (a > 0.f) ? a : NEG * a; }

// ---------------------------------------------------------------------------
// LDS-staged bf16 MFMA GEMM body with fused attention logits (proven R5 code;
// R6 lesson: register-direct fragment loads split into ~64 lines/instr —
// LDS staging exists to coalesce them. Do not remove.)
// ---------------------------------------------------------------------------
#define PITCH 40
template<int BN, int FM, int FN, bool CVT, bool FP8OUT, bool L4>
__device__ __forceinline__ void mfma_body(int bx, int by,
                                          const void* __restrict__ Araw,
                                          const unsigned short* __restrict__ Bt,
                                          void* __restrict__ Cout,
                                          const float* __restrict__ a_s,
                                          const float* __restrict__ a_d,
                                          float* __restrict__ als,
                                          float* __restrict__ ald,
                                          int M, int K, int Ncol) {
    __shared__ unsigned short As[128 * PITCH];
    __shared__ unsigned short Bs[BN * PITCH];
    const int WCOLS = BN / (FN * 16);
    int tid = threadIdx.x;
    int wave = tid >> 6, lane = tid & 63;
    int quad = lane >> 4, l16 = lane & 15;
    int wr = wave / WCOLS, wc = wave % WCOLS;
    long row0 = (long)bx * 128;
    int col0 = by * BN;

    f32x4 acc[FM][FN] = {};

    for (int k0 = 0; k0 < K; k0 += 32) {
        for (int c = tid; c < 512; c += 256) {
            int r = c >> 2, kp = (c & 3) << 3;
            long gr = row0 + r;
            if (CVT) {
                const float* A32 = (const float*)Araw;
                ushort4 lo = {0,0,0,0}, hi = {0,0,0,0};
                if (gr < M) {
                    float4 v0 = *(const float4*)(A32 + gr * K + k0 + kp);
                    float4 v1 = *(const float4*)(A32 + gr * K + k0 + kp + 4);
                    lo.x = f2bf(v0.x); lo.y = f2bf(v0.y); lo.z = f2bf(v0.z); lo.w = f2bf(v0.w);
                    hi.x = f2bf(v1.x); hi.y = f2bf(v1.y); hi.z = f2bf(v1.z); hi.w = f2bf(v1.w);
                }
                *(ushort4*)(As + r * PITCH + kp) = lo;
                *(ushort4*)(As + r * PITCH + kp + 4) = hi;
            } else {
                const unsigned short* A16 = (const unsigned short*)Araw;
                uint4 v = {0u, 0u, 0u, 0u};
                if (gr < M) v = *(const uint4*)(A16 + gr * K + k0 + kp);
                *(uint4*)(As + r * PITCH + kp) = v;
            }
        }
        for (int c = tid; c < BN * 4; c += 256) {
            int r = c >> 2, kp = (c & 3) << 3;
            uint4 v = *(const uint4*)(Bt + (long)(col0 + r) * K + k0 + kp);
            *(uint4*)(Bs + r * PITCH + kp) = v;
        }
        __syncthreads();
        bf16x8 af[FM], bfr[FN];
        #pragma unroll
        for (int i = 0; i < FM; ++i)
            af[i] = *(const bf16x8*)(As + (wr * FM * 16 + i * 16 + l16) * PITCH + quad * 8);
        #pragma unroll
        for (int j = 0; j < FN; ++j)
            bfr[j] = *(const bf16x8*)(Bs + (wc * FN * 16 + j * 16 + l16) * PITCH + quad * 8);
        #pragma unroll
        for (int i = 0; i < FM; ++i)
            #pragma unroll
            for (int j = 0; j < FN; ++j)
                acc[i][j] = __builtin_amdgcn_mfma_f32_16x16x32_bf16(af[i], bfr[j], acc[i][j], 0, 0, 0);
        __syncthreads();
    }

    // fused logits
    {
        int head = L4 ? (by * WCOLS + wc) : 0;
        float as_v[FN], ad_v[FN];
        #pragma unroll
        for (int j = 0; j < FN; ++j) {
            int cidx = j * 16 + l16;
            if (L4) {
                as_v[j] = a_s[head * 64 + cidx];
                ad_v[j] = a_d[head * 64 + cidx];
            } else {
                as_v[j] = (cidx < OUT_CH) ? a_s[cidx] : 0.f;
                ad_v[j] = (cidx < OUT_CH) ? a_d[cidx] : 0.f;
            }
        }
        #pragma unroll
        for (int i = 0; i < FM; ++i) {
            #pragma unroll
            for (int v = 0; v < 4; ++v) {
                float ps = acc[i][0][v] * as_v[0] + acc[i][1][v] * as_v[1]
                         + acc[i][2][v] * as_v[2] + acc[i][3][v] * as_v[3];
                float pd = acc[i][0][v] * ad_v[0] + acc[i][1][v] * ad_v[1]
                         + acc[i][2][v] * ad_v[2] + acc[i][3][v] * ad_v[3];
                #pragma unroll
                for (int off = 1; off < 16; off <<= 1) {
                    ps += __shfl_xor(ps, off);
                    pd += __shfl_xor(pd, off);
                }
                if (l16 == 0) {
                    long row = row0 + wr * (FM * 16) + i * 16 + quad * 4 + v;
                    if (row < M) {
                        if (L4) { als[row * 4 + head] = ps; ald[row * 4 + head] = pd; }
                        else    { als[row] = ps; ald[row] = pd; }
                    }
                }
            }
        }
    }

    if (FP8OUT) {
        unsigned char* C8 = (unsigned char*)Cout;
        #pragma unroll
        for (int i = 0; i < FM; ++i) {
            #pragma unroll
            for (int v = 0; v < 4; ++v) {
                long row = row0 + wr * FM * 16 + i * 16 + quad * 4 + v;
                if (row < M) {
                    int p01 = __builtin_amdgcn_cvt_pk_fp8_f32(acc[i][0][v], acc[i][1][v], 0, false);
                    int p23 = __builtin_amdgcn_cvt_pk_fp8_f32(acc[i][2][v], acc[i][3][v], 0, false);
                    unsigned char* b = C8 + row * 256 + col0 + wc * (FN * 16) + l16;
                    b[0]  = (unsigned char)(p01 & 0xFF);
                    b[16] = (unsigned char)((p01 >> 8) & 0xFF);
                    b[32] = (unsigned char)(p23 & 0xFF);
                    b[48] = (unsigned char)((p23 >> 8) & 0xFF);
                }
            }
        }
    } else {
        unsigned short* C = (unsigned short*)Cout;
        #pragma unroll
        for (int i = 0; i < FM; ++i) {
            long rowb = row0 + wr * FM * 16 + i * 16 + quad * 4;
            #pragma unroll
            for (int j = 0; j < FN; ++j) {
                int col = col0 + wc * FN * 16 + j * 16 + l16;
                if (col < Ncol) {
                    #pragma unroll
                    for (int v = 0; v < 4; ++v) {
                        long r = rowb + v;
                        if (r < M) C[r * Ncol + col] = f2bf(acc[i][j][v]);
                    }
                }
            }
        }
    }
}

// Standalone GEMM kernel (layers 2 and 3).
template<int BN, int FM, int FN, bool CVT, bool FP8OUT, bool L4>
__global__ __launch_bounds__(256) void k_mfma(const void* __restrict__ Araw,
                                              const unsigned short* __restrict__ Bt,
                                              void* __restrict__ Cout,
                                              const float* __restrict__ a_s,
                                              const float* __restrict__ a_d,
                                              float* __restrict__ als,
                                              float* __restrict__ ald,
                                              int M, int K, int Ncol) {
    mfma_body<BN, FM, FN, CVT, FP8OUT, L4>(blockIdx.x, blockIdx.y,
                                           Araw, Bt, Cout, a_s, a_d, als, ald, M, K, Ncol);
}

// ---------------------------------------------------------------------------
// Front kernel: edge bucketing (blocks [0,256)) + ALL weight transposes
// ([256,704)). GEMM1 moved to k_mid (paired with the CSR finalize).
// ---------------------------------------------------------------------------
__global__ __launch_bounds__(256) void k_front(const int* __restrict__ ei,
                                               int* __restrict__ fcur,
                                               unsigned int* __restrict__ fbuf,
                                               const float* __restrict__ W1,
                                               const float* __restrict__ W2,
                                               const float* __restrict__ W3,
                                               unsigned short* __restrict__ Wt1,
                                               unsigned short* __restrict__ Wt2,
                                               unsigned short* __restrict__ Wt3) {
    int b = blockIdx.x;
    if (b >= 256) {
        int i = (b - 256) * 256 + threadIdx.x;
        if (i < 32768) {                       // W1: 256 x 128
            int n = i >> 7, k = i & 127;
            Wt1[i] = f2bf(W1[(long)k * 256 + n]);
        } else if (i < 98304) {                // W2: 256 x 256
            int j = i - 32768;
            int n = j >> 8, k = j & 255;
            Wt2[j] = f2bf(W2[(long)k * 256 + n]);
        } else if (i < 114688) {               // W3: 64(pad) x 256
            int j = i - 98304;
            int n = j >> 8, k = j & 255;
            Wt3[j] = (n < OUT_CH) ? f2bf(W3[(long)k * OUT_CH + n]) : (unsigned short)0;
        }
        return;
    }
    // ---- edge bucketing ----
    __shared__ int lcnt[NFINE], lbase[NFINE], lcur[NFINE];
    int tid = threadIdx.x;
    for (int i = tid; i < NFINE; i += 256) lcnt[i] = 0;
    __syncthreads();
    for (int i = b * 256 + tid; i < ETOT; i += 256 * 256) {
        int d = (i < N_EDGES) ? ei[N_EDGES + i] : (i - N_EDGES);
        atomicAdd(&lcnt[d / NPF], 1);
    }
    __syncthreads();
    for (int i = tid; i < NFINE; i += 256) {
        lbase[i] = atomicAdd(&fcur[i], lcnt[i]);
        lcur[i] = 0;
    }
    __syncthreads();
    for (int i = b * 256 + tid; i < ETOT; i += 256 * 256) {
        int s, d;
        if (i < N_EDGES) { s = ei[i]; d = ei[N_EDGES + i]; }
        else             { s = i - N_EDGES; d = s; }
        int p = d / NPF;
        int off = atomicAdd(&lcur[p], 1);
        fbuf[(long)p * FCAP + lbase[p] + off] = (unsigned int)s | ((unsigned int)d << 16);
    }
}

// ---------------------------------------------------------------------------
// Mid kernel: CSR finalize (blocks [0,512)) PARALLEL WITH layer-1 GEMM
// ([512, 512+2*MBLK)). Independent: build reads fcur/fbuf, GEMM reads x/Wt1.
// Hides build's ~18us under the GEMM.
// ---------------------------------------------------------------------------
__global__ __launch_bounds__(256) void k_mid(const int* __restrict__ fcur,
                                             const unsigned int* __restrict__ fbuf,
                                             int* __restrict__ deg,
                                             int* __restrict__ gcur,
                                             int* __restrict__ start,
                                             int* __restrict__ eSrc,
                                             const float* __restrict__ x,
                                             const unsigned short* __restrict__ Wt1,
                                             unsigned char* __restrict__ hA8,
                                             const float* __restrict__ as1,
                                             const float* __restrict__ ad1,
                                             float* __restrict__ als,
                                             float* __restrict__ ald) {
    int b = blockIdx.x;
    if (b >= NFINE) {
        int g = b - NFINE;
        mfma_body<128, 4, 4, true, true, true>(g % MBLK, g / MBLK,
                                               x, Wt1, hA8, as1, ad1, als, ald,
                                               N_NODES, IN_CH, 256);
        return;
    }
    // ---- CSR finalize: count + scan + global base + scatter + pad ----
    __shared__ int cnt[NPF];
    __shared__ int sval[128];
    __shared__ int offs[NPF];
    __shared__ int base_[NPF];
    __shared__ int pbase;
    int f = b;
    int tid = threadIdx.x;
    int n0 = f * NPF;
    int nend = min(n0 + NPF, N_NODES);
    int nn = nend - n0;
    if (tid < NPF) cnt[tid] = 0;
    __syncthreads();
    int n = fcur[f];
    for (int i = tid; i < n; i += 256)
        atomicAdd(&cnt[(int)(fbuf[(long)f * FCAP + i] >> 16) - n0], 1);
    __syncthreads();
    int pd = 0;
    if (tid < 128) {
        pd = (tid < nn) ? ((cnt[tid] + 7) & ~7) : 0;   // pad-8
        sval[tid] = pd;
    }
    __syncthreads();
    #pragma unroll
    for (int off = 1; off < 128; off <<= 1) {
        int t = 0;
        if (tid < 128 && tid >= off) t = sval[tid - off];
        __syncthreads();
        if (tid < 128) sval[tid] += t;
        __syncthreads();
    }
    if (tid == 0) pbase = atomicAdd(gcur, sval[127]);  // partition base, order-free
    __syncthreads();
    if (tid < nn) {
        int st = pbase + sval[tid] - pd;               // exclusive
        deg[n0 + tid] = cnt[tid];
        start[n0 + tid] = st;
        offs[tid] = st;
        base_[tid] = st;
    }
    __syncthreads();
    for (int i = tid; i < n; i += 256) {
        unsigned int u = fbuf[(long)f * FCAP + i];
        int d = (int)(u >> 16);
        int pos = atomicAdd(&offs[d - n0], 1);
        eSrc[pos] = (int)(u & 0xFFFFu);
    }
    __syncthreads();
    if (tid < nn) {
        int endp = offs[tid];
        int dg = endp - base_[tid];
        int stop = base_[tid] + ((dg + 7) & ~7);
        for (int k2 = endp; k2 < stop; ++k2) eSrc[k2] = -1;
    }
}

// ---------------------------------------------------------------------------
// Aggregation (4-head): quarter-wave per edge (16 lanes x uint4 = 256B/row),
// 16 ch/lane, split sbuf/wbuf LDS (conflict-free). At the gather-serve floor
// (~44.5us) — three structures all pin here; do not restructure further.
// ---------------------------------------------------------------------------
__global__ __launch_bounds__(256) void k_agg4(const unsigned char* __restrict__ h8,
                                              const int* __restrict__ start,
                                              const int* __restrict__ deg,
                                              const int* __restrict__ eSrc,
                                              const float* __restrict__ als,
                                              const float* __restrict__ ald,
                                              const float* __restrict__ bias,
                                              unsigned short* __restrict__ out) {
    __shared__ float wbuf[4][CAP * 4];
    __shared__ int   sbuf[4][CAP];       // pre-scaled src byte offset (ss<<8)
    int wid = threadIdx.x >> 6;
    int node = (blockIdx.x * blockDim.x + threadIdx.x) >> 6;
    int lane = threadIdx.x & 63;
    if (node >= N_NODES) return;
    int st = start[node];
    int dgp = (deg[node] + 7) & ~7;
    const int* ep = eSrc + st;

    // ---- phase 1: weights into LDS ----
    int l16 = lane & 15, headw = lane >> 4;
    float aldd4 = ald[node * 4 + headw];
    int ncap = (dgp < CAP) ? dgp : CAP;
    for (int c = 0; c < ncap; c += 16) {
        int slot = c + l16;
        bool ok = (slot < ncap);
        int raw = ok ? ep[slot] : -1;
        int ss = (raw < 0) ? 0 : raw;
        float a = als[(long)ss * 4 + headw] + aldd4;
        float w = (raw < 0) ? 0.f : __expf(lrelu(a));
        if (ok) {
            wbuf[wid][slot * 4 + headw] = w;
            if (headw == 0) sbuf[wid][slot] = ss << 8;
        }
    }

    // ---- phase 2: quarter-wave per edge, 16 ch/lane (fp8 uint4) ----
    int q = lane >> 4;                   // quarter index = edge sub-slot
    int head = l16 >> 2;                 // 4 lanes per head
    const unsigned char* hb = h8 + l16 * 16;
    float den = 0.f;
    f32x2 acc2[8] = {};

    for (int j = 0; j < ncap; j += 8) {
        int  s0 = sbuf[wid][j + q];
        int  s1 = sbuf[wid][j + 4 + q];
        float w0 = wbuf[wid][(j + q) * 4 + head];
        float w1 = wbuf[wid][(j + 4 + q) * 4 + head];
        uint4 h0 = *(const uint4*)(hb + (long)s0);
        uint4 h1 = *(const uint4*)(hb + (long)s1);
        den += w0 + w1;
        f32x2 W0; W0.x = w0; W0.y = w0;
        f32x2 W1; W1.x = w1; W1.y = w1;
        acc2[0] += W0 * __builtin_amdgcn_cvt_pk_f32_fp8((int)h0.x, false);
        acc2[1] += W0 * __builtin_amdgcn_cvt_pk_f32_fp8((int)h0.x, true);
        acc2[2] += W0 * __builtin_amdgcn_cvt_pk_f32_fp8((int)h0.y, false);
        acc2[3] += W0 * __builtin_amdgcn_cvt_pk_f32_fp8((int)h0.y, true);
        acc2[4] += W0 * __builtin_amdgcn_cvt_pk_f32_fp8((int)h0.z, false);
        acc2[5] += W0 * __builtin_amdgcn_cvt_pk_f32_fp8((int)h0.z, true);
        acc2[6] += W0 * __builtin_amdgcn_cvt_pk_f32_fp8((int)h0.w, false);
        acc2[7] += W0 * __builtin_amdgcn_cvt_pk_f32_fp8((int)h0.w, true);
        acc2[0] += W1 * __builtin_amdgcn_cvt_pk_f32_fp8((int)h1.x, false);
        acc2[1] += W1 * __builtin_amdgcn_cvt_pk_f32_fp8((int)h1.x, true);
        acc2[2] += W1 * __builtin_amdgcn_cvt_pk_f32_fp8((int)h1.y, false);
        acc2[3] += W1 * __builtin_amdgcn_cvt_pk_f32_fp8((int)h1.y, true);
        acc2[4] += W1 * __builtin_amdgcn_cvt_pk_f32_fp8((int)h1.z, false);
        acc2[5] += W1 * __builtin_amdgcn_cvt_pk_f32_fp8((int)h1.z, true);
        acc2[6] += W1 * __builtin_amdgcn_cvt_pk_f32_fp8((int)h1.w, false);
        acc2[7] += W1 * __builtin_amdgcn_cvt_pk_f32_fp8((int)h1.w, true);
    }

    if (dgp > ncap) {                    // overflow (deg > 64: ~never)
        float alddq = ald[node * 4 + head];
        for (int j = ncap; j < dgp; j += 4) {
            int raw = ep[j + q];
            int ss = (raw < 0) ? 0 : raw;
            float w = (raw < 0) ? 0.f : __expf(lrelu(als[(long)ss * 4 + head] + alddq));
            uint4 hv = *(const uint4*)(h8 + ((long)ss << 8) + l16 * 16);
            den += w;
            f32x2 W0; W0.x = w; W0.y = w;
            acc2[0] += W0 * __builtin_amdgcn_cvt_pk_f32_fp8((int)hv.x, false);
            acc2[1] += W0 * __builtin_amdgcn_cvt_pk_f32_fp8((int)hv.x, true);
            acc2[2] += W0 * __builtin_amdgcn_cvt_pk_f32_fp8((int)hv.y, false);
            acc2[3] += W0 * __builtin_amdgcn_cvt_pk_f32_fp8((int)hv.y, true);
            acc2[4] += W0 * __builtin_amdgcn_cvt_pk_f32_fp8((int)hv.z, false);
            acc2[5] += W0 * __builtin_amdgcn_cvt_pk_f32_fp8((int)hv.z, true);
            acc2[6] += W0 * __builtin_amdgcn_cvt_pk_f32_fp8((int)hv.w, false);
            acc2[7] += W0 * __builtin_amdgcn_cvt_pk_f32_fp8((int)hv.w, true);
        }
    }

    // reduce across the 4 quarters (lanes with equal l16)
    den += __shfl_xor(den, 16);
    den += __shfl_xor(den, 32);
    #pragma unroll
    for (int c = 0; c < 8; ++c) {
        acc2[c].x += __shfl_xor(acc2[c].x, 16);
        acc2[c].y += __shfl_xor(acc2[c].y, 16);
        acc2[c].x += __shfl_xor(acc2[c].x, 32);
        acc2[c].y += __shfl_xor(acc2[c].y, 32);
    }

    if (q == 0) {
        float inv = 1.f / den;
        int cb = l16 * 16;
        float4 b0 = *(const float4*)(bias + cb);
        float4 b1 = *(const float4*)(bias + cb + 4);
        float4 b2 = *(const float4*)(bias + cb + 8);
        float4 b3 = *(const float4*)(bias + cb + 12);
        float v0  = fmaxf(acc2[0].x * inv + b0.x, 0.f);
        float v1  = fmaxf(acc2[0].y * inv + b0.y, 0.f);
        float v2  = fmaxf(acc2[1].x * inv + b0.z, 0.f);
        float v3  = fmaxf(acc2[1].y * inv + b0.w, 0.f);
        float v4  = fmaxf(acc2[2].x * inv + b1.x, 0.f);
        float v5  = fmaxf(acc2[2].y * inv + b1.y, 0.f);
        float v6  = fmaxf(acc2[3].x * inv + b1.z, 0.f);
        float v7  = fmaxf(acc2[3].y * inv + b1.w, 0.f);
        float v8  = fmaxf(acc2[4].x * inv + b2.x, 0.f);
        float v9  = fmaxf(acc2[4].y * inv + b2.y, 0.f);
        float v10 = fmaxf(acc2[5].x * inv + b2.z, 0.f);
        float v11 = fmaxf(acc2[5].y * inv + b2.w, 0.f);
        float v12 = fmaxf(acc2[6].x * inv + b3.x, 0.f);
        float v13 = fmaxf(acc2[6].y * inv + b3.y, 0.f);
        float v14 = fmaxf(acc2[7].x * inv + b3.z, 0.f);
        float v15 = fmaxf(acc2[7].y * inv + b3.w, 0.f);
        uint4 o0, o1;
        o0.x = (unsigned int)f2bf(v0)  | ((unsigned int)f2bf(v1)  << 16);
        o0.y = (unsigned int)f2bf(v2)  | ((unsigned int)f2bf(v3)  << 16);
        o0.z = (unsigned int)f2bf(v4)  | ((unsigned int)f2bf(v5)  << 16);
        o0.w = (unsigned int)f2bf(v6)  | ((unsigned int)f2bf(v7)  << 16);
        o1.x = (unsigned int)f2bf(v8)  | ((unsigned int)f2bf(v9)  << 16);
        o1.y = (unsigned int)f2bf(v10) | ((unsigned int)f2bf(v11) << 16);
        o1.z = (unsigned int)f2bf(v12) | ((unsigned int)f2bf(v13) << 16);
        o1.w = (unsigned int)f2bf(v14) | ((unsigned int)f2bf(v15) << 16);
        *(uint4*)(out + (long)node * 256 + cb) = o0;
        *(uint4*)(out + (long)node * 256 + cb + 8) = o1;
    }
}

// ---------------------------------------------------------------------------
// Final layer agg (exact proven R14 version, pad-8).
// ---------------------------------------------------------------------------
__global__ __launch_bounds__(256) void k_agg1(const unsigned short* __restrict__ h,
                                              const int* __restrict__ start,
                                              const int* __restrict__ deg,
                                              const int* __restrict__ eSrc,
                                              const float* __restrict__ als,
                                              const float* __restrict__ ald,
                                              const float* __restrict__ bias,
                                              float* __restrict__ out) {
    int node = (blockIdx.x * blockDim.x + threadIdx.x) >> 6;
    int lane = threadIdx.x & 63;
    if (node >= N_NODES) return;
    int q = lane >> 4, r = lane & 15;
    bool act = (r < 10);
    int st = start[node];
    int dgp = (deg[node] + 7) & ~7;
    const int* ep = eSrc + st;
    float aldd = ald[node];

    float den = 0.f;
    float4 acc = {0.f, 0.f, 0.f, 0.f};

    int j = 0;
    for (; j + 16 <= dgp; j += 16) {
        int base = j + q * 4;
        int s[4];
        float w[4];
        #pragma unroll
        for (int u = 0; u < 4; ++u) s[u] = ep[base + u];
        #pragma unroll
        for (int u = 0; u < 4; ++u) {
            int raw = s[u];
            int ss = (raw < 0) ? 0 : raw;
            w[u] = (raw < 0) ? 0.f : __expf(lrelu(als[ss] + aldd));
            s[u] = ss;
        }
        ushort4 hh[4];
        #pragma unroll
        for (int u = 0; u < 4; ++u) {
            ushort4 t = {0, 0, 0, 0};
            if (act) t = *(const ushort4*)(h + (long)s[u] * OUT_CH + r * 4);
            hh[u] = t;
        }
        #pragma unroll
        for (int u = 0; u < 4; ++u) {
            den += w[u];
            acc.x += w[u] * bf2f(hh[u].x);
            acc.y += w[u] * bf2f(hh[u].y);
            acc.z += w[u] * bf2f(hh[u].z);
            acc.w += w[u] * bf2f(hh[u].w);
        }
    }
    if (j < dgp) {
        int base = j + q * 2;
        int s[2];
        float w[2];
        #pragma unroll
        for (int u = 0; u < 2; ++u) s[u] = ep[base + u];
        #pragma unroll
        for (int u = 0; u < 2; ++u) {
            int raw = s[u];
            int ss = (raw < 0) ? 0 : raw;
            w[u] = (raw < 0) ? 0.f : __expf(lrelu(als[ss] + aldd));
            s[u] = ss;
        }
        ushort4 hh[2];
        #pragma unroll
        for (int u = 0; u < 2; ++u) {
            ushort4 t = {0, 0, 0, 0};
            if (act) t = *(const ushort4*)(h + (long)s[u] * OUT_CH + r * 4);
            hh[u] = t;
        }
        #pragma unroll
        for (int u = 0; u < 2; ++u) {
            den += w[u];
            acc.x += w[u] * bf2f(hh[u].x);
            acc.y += w[u] * bf2f(hh[u].y);
            acc.z += w[u] * bf2f(hh[u].z);
            acc.w += w[u] * bf2f(hh[u].w);
        }
    }

    #pragma unroll
    for (int off = 16; off < 64; off <<= 1) {
        acc.x += __shfl_xor(acc.x, off);
        acc.y += __shfl_xor(acc.y, off);
        acc.z += __shfl_xor(acc.z, off);
        acc.w += __shfl_xor(acc.w, off);
        den   += __shfl_xor(den, off);
    }
    float inv = 1.f / den;
    float4 bv = {0.f, 0.f, 0.f, 0.f};
    if (act) bv = *(const float4*)(bias + r * 4);
    float4 v;
    v.x = acc.x * inv + bv.x;
    v.y = acc.y * inv + bv.y;
    v.z = acc.z * inv + bv.z;
    v.w = acc.w * inv + bv.w;
    float mx = act ? fmaxf(fmaxf(v.x, v.y), fmaxf(v.z, v.w)) : -INFINITY;
    #pragma unroll
    for (int off = 1; off < 16; off <<= 1) mx = fmaxf(mx, __shfl_xor(mx, off));
    float sum = act ? (__expf(v.x - mx) + __expf(v.y - mx) + __expf(v.z - mx) + __expf(v.w - mx)) : 0.f;
    #pragma unroll
    for (int off = 1; off < 16; off <<= 1) sum += __shfl_xor(sum, off);
    float lse = mx + logf(sum);
    if (q == 0 && act) {
        float4 o;
        o.x = v.x - lse;
        o.y = v.y - lse;
        o.z = v.z - lse;
        o.w = v.w - lse;
        *(float4*)(out + (long)node * OUT_CH + r * 4) = o;
    }
}

// ---------------------------------------------------------------------------
extern "C" void kernel_launch(void* const* d_in, const int* in_sizes, int n_in,
                              void* d_out, int out_size, void* d_ws, size_t ws_size,
                              hipStream_t stream) {
    (void)in_sizes; (void)n_in; (void)out_size; (void)ws_size;
    const float* x   = (const float*)d_in[0];
    const int*   ei  = (const int*)d_in[1];
    const float* W1  = (const float*)d_in[2];
    const float* as1 = (const float*)d_in[3];
    const float* ad1 = (const float*)d_in[4];
    const float* b1  = (const float*)d_in[5];
    const float* W2  = (const float*)d_in[6];
    const float* as2 = (const float*)d_in[7];
    const float* ad2 = (const float*)d_in[8];
    const float* b2  = (const float*)d_in[9];
    const float* W3  = (const float*)d_in[10];
    const float* as3 = (const float*)d_in[11];
    const float* ad3 = (const float*)d_in[12];
    const float* b3  = (const float*)d_in[13];
    float* out = (float*)d_out;

    char* p = (char*)d_ws;
    auto alloc = [&](size_t b) { char* r = p; p += (b + 255) & ~(size_t)255; return r; };
    int*   deg   = (int*)alloc((size_t)N_NODES * 4);
    int*   start = (int*)alloc((size_t)N_NODES * 4);
    int*   psum  = (int*)alloc((size_t)NFINE * 4);   // psum[0] = global cursor
    int*   fcur  = (int*)alloc((size_t)NFINE * 4);   // adjacent to psum (both 2048B, 256-aligned)
    unsigned int* fbuf = (unsigned int*)alloc((size_t)NFINE * FCAP * 4);
    int*   eSrc  = (int*)alloc((size_t)EPAD_MAX * 4);
    float* als   = (float*)alloc((size_t)N_NODES * 4 * 4);
    float* ald   = (float*)alloc((size_t)N_NODES * 4 * 4);
    unsigned char*  hA8  = (unsigned char*)alloc((size_t)N_NODES * 256);
    unsigned short* hBbf = (unsigned short*)alloc((size_t)N_NODES * 256 * 2);
    unsigned short* h3bf = (unsigned short*)alloc((size_t)N_NODES * OUT_CH * 2);
    unsigned short* Wt1  = (unsigned short*)alloc((size_t)256 * IN_CH * 2);
    unsigned short* Wt2  = (unsigned short*)alloc((size_t)256 * 256 * 2);
    unsigned short* Wt3  = (unsigned short*)alloc((size_t)64 * 256 * 2);

    const int WB = (N_NODES + 3) / 4;

    // ---- front: memset, then {bucketing || all transposes} ----
    hipMemsetAsync(psum, 0, (size_t)NFINE * 8, stream);
    k_front<<<704, 256, 0, stream>>>(ei, fcur, fbuf, W1, W2, W3, Wt1, Wt2, Wt3);

    // ---- mid: {CSR finalize || layer-1 GEMM} ----
    k_mid<<<NFINE + 2 * MBLK, 256, 0, stream>>>(fcur, fbuf, deg, psum, start, eSrc,
                                                x, Wt1, hA8, as1, ad1, als, ald);

    // ---- layer 1 aggregation ----
    k_agg4<<<WB, 256, 0, stream>>>(hA8, start, deg, eSrc, als, ald, b1, hBbf);

    // ---- layer 2 (bf16 in, fp8 out, fused logits) ----
    k_mfma<128, 4, 4, false, true, true><<<dim3(MBLK, 2), 256, 0, stream>>>(
        hBbf, Wt2, hA8, as2, ad2, als, ald, N_NODES, 256, 256);
    k_agg4<<<WB, 256, 0, stream>>>(hA8, start, deg, eSrc, als, ald, b2, hBbf);

    // ---- layer 3 (bf16 in, bf16 out, fused single-head logits) ----
    k_mfma<64, 2, 4, false, false, false><<<dim3(MBLK, 1), 256, 0, stream>>>(
        hBbf, Wt3, h3bf, as3, ad3, als, ald, N_NODES, 256, OUT_CH);
    k_agg1<<<WB, 256, 0, stream>>>(h3bf, start, deg, eSrc, als, ald, b3, out);
}

// Round 8
// 292.600 us; speedup vs baseline: 1.0973x; 1.0611x over previous
//
#include <hip/hip_runtime.h>
#include <math.h>

#define N_NODES 50000
#define N_EDGES 800000
#define ETOT    (N_EDGES + N_NODES)
#define EPAD_MAX 1200000
#define IN_CH   128
#define OUT_CH  40
#define NEG     0.2f
#define CAP     64         // max cached slots per node (Poisson(17) max ~48)

// single-level bucketed CSR
#define NPF   98           // nodes per fine partition
#define NFINE 512          // 512*98 = 50176 >= 50000
#define FCAP  2400         // capacity per fine (mean ~1666)

#define MBLK  ((N_NODES + 127) / 128)   // 391 row-blocks for the GEMMs

typedef __attribute__((ext_vector_type(8))) short bf16x8;
typedef __attribute__((ext_vector_type(4))) float f32x4;
typedef __attribute__((ext_vector_type(2))) float f32x2;

__device__ inline unsigned short f2bf(float f) {
    unsigned int u = __float_as_uint(f);
    return (unsigned short)((u + 0x7FFFu + ((u >> 16) & 1u)) >> 16);
}
__device__ inline float bf2f(unsigned short u) {
    return __uint_as_float((unsigned int)u << 16);
}
__device__ inline float lrelu(float a) { return (a > 0.f) ? a : NEG * a; }

// ---------------------------------------------------------------------------
// LDS-staged bf16 MFMA GEMM body with fused attention logits.
// Single-A-pass version: BN=256 + 512 threads (8 waves, 2 row x 4 col) stages
// the A-tile ONCE per k0 for all 256 columns — halves A traffic vs grid.y=2.
// Staging loops stride by blockDim.x so the 256-thread BN=64 instance works.
// MFMA order per output element unchanged -> bit-identical results.
// (R6 lesson: register-direct fragment loads split into ~64 lines/instr —
// LDS staging exists to coalesce them. Do not remove.)
// ---------------------------------------------------------------------------
#define PITCH 40
template<int BN, int FM, int FN, bool CVT, bool FP8OUT, bool L4>
__device__ __forceinline__ void mfma_body(int bx, int by,
                                          const void* __restrict__ Araw,
                                          const unsigned short* __restrict__ Bt,
                                          void* __restrict__ Cout,
                                          const float* __restrict__ a_s,
                                          const float* __restrict__ a_d,
                                          float* __restrict__ als,
                                          float* __restrict__ ald,
                                          int M, int K, int Ncol) {
    __shared__ unsigned short As[128 * PITCH];
    __shared__ unsigned short Bs[BN * PITCH];
    const int WCOLS = BN / (FN * 16);
    int tid = threadIdx.x;
    int nt = blockDim.x;
    int wave = tid >> 6, lane = tid & 63;
    int quad = lane >> 4, l16 = lane & 15;
    int wr = wave / WCOLS, wc = wave % WCOLS;
    long row0 = (long)bx * 128;
    int col0 = by * BN;

    f32x4 acc[FM][FN] = {};

    for (int k0 = 0; k0 < K; k0 += 32) {
        for (int c = tid; c < 512; c += nt) {
            int r = c >> 2, kp = (c & 3) << 3;
            long gr = row0 + r;
            if (CVT) {
                const float* A32 = (const float*)Araw;
                ushort4 lo = {0,0,0,0}, hi = {0,0,0,0};
                if (gr < M) {
                    float4 v0 = *(const float4*)(A32 + gr * K + k0 + kp);
                    float4 v1 = *(const float4*)(A32 + gr * K + k0 + kp + 4);
                    lo.x = f2bf(v0.x); lo.y = f2bf(v0.y); lo.z = f2bf(v0.z); lo.w = f2bf(v0.w);
                    hi.x = f2bf(v1.x); hi.y = f2bf(v1.y); hi.z = f2bf(v1.z); hi.w = f2bf(v1.w);
                }
                *(ushort4*)(As + r * PITCH + kp) = lo;
                *(ushort4*)(As + r * PITCH + kp + 4) = hi;
            } else {
                const unsigned short* A16 = (const unsigned short*)Araw;
                uint4 v = {0u, 0u, 0u, 0u};
                if (gr < M) v = *(const uint4*)(A16 + gr * K + k0 + kp);
                *(uint4*)(As + r * PITCH + kp) = v;
            }
        }
        for (int c = tid; c < BN * 4; c += nt) {
            int r = c >> 2, kp = (c & 3) << 3;
            uint4 v = *(const uint4*)(Bt + (long)(col0 + r) * K + k0 + kp);
            *(uint4*)(Bs + r * PITCH + kp) = v;
        }
        __syncthreads();
        bf16x8 af[FM], bfr[FN];
        #pragma unroll
        for (int i = 0; i < FM; ++i)
            af[i] = *(const bf16x8*)(As + (wr * FM * 16 + i * 16 + l16) * PITCH + quad * 8);
        #pragma unroll
        for (int j = 0; j < FN; ++j)
            bfr[j] = *(const bf16x8*)(Bs + (wc * FN * 16 + j * 16 + l16) * PITCH + quad * 8);
        #pragma unroll
        for (int i = 0; i < FM; ++i)
            #pragma unroll
            for (int j = 0; j < FN; ++j)
                acc[i][j] = __builtin_amdgcn_mfma_f32_16x16x32_bf16(af[i], bfr[j], acc[i][j], 0, 0, 0);
        __syncthreads();
    }

    // fused logits
    {
        int head = L4 ? (by * WCOLS + wc) : 0;
        float as_v[FN], ad_v[FN];
        #pragma unroll
        for (int j = 0; j < FN; ++j) {
            int cidx = j * 16 + l16;
            if (L4) {
                as_v[j] = a_s[head * 64 + cidx];
                ad_v[j] = a_d[head * 64 + cidx];
            } else {
                as_v[j] = (cidx < OUT_CH) ? a_s[cidx] : 0.f;
                ad_v[j] = (cidx < OUT_CH) ? a_d[cidx] : 0.f;
            }
        }
        #pragma unroll
        for (int i = 0; i < FM; ++i) {
            #pragma unroll
            for (int v = 0; v < 4; ++v) {
                float ps = acc[i][0][v] * as_v[0] + acc[i][1][v] * as_v[1]
                         + acc[i][2][v] * as_v[2] + acc[i][3][v] * as_v[3];
                float pd = acc[i][0][v] * ad_v[0] + acc[i][1][v] * ad_v[1]
                         + acc[i][2][v] * ad_v[2] + acc[i][3][v] * ad_v[3];
                #pragma unroll
                for (int off = 1; off < 16; off <<= 1) {
                    ps += __shfl_xor(ps, off);
                    pd += __shfl_xor(pd, off);
                }
                if (l16 == 0) {
                    long row = row0 + wr * (FM * 16) + i * 16 + quad * 4 + v;
                    if (row < M) {
                        if (L4) { als[row * 4 + head] = ps; ald[row * 4 + head] = pd; }
                        else    { als[row] = ps; ald[row] = pd; }
                    }
                }
            }
        }
    }

    if (FP8OUT) {
        unsigned char* C8 = (unsigned char*)Cout;
        #pragma unroll
        for (int i = 0; i < FM; ++i) {
            #pragma unroll
            for (int v = 0; v < 4; ++v) {
                long row = row0 + wr * FM * 16 + i * 16 + quad * 4 + v;
                if (row < M) {
                    int p01 = __builtin_amdgcn_cvt_pk_fp8_f32(acc[i][0][v], acc[i][1][v], 0, false);
                    int p23 = __builtin_amdgcn_cvt_pk_fp8_f32(acc[i][2][v], acc[i][3][v], 0, false);
                    unsigned char* b = C8 + row * 256 + col0 + wc * (FN * 16) + l16;
                    b[0]  = (unsigned char)(p01 & 0xFF);
                    b[16] = (unsigned char)((p01 >> 8) & 0xFF);
                    b[32] = (unsigned char)(p23 & 0xFF);
                    b[48] = (unsigned char)((p23 >> 8) & 0xFF);
                }
            }
        }
    } else {
        unsigned short* C = (unsigned short*)Cout;
        #pragma unroll
        for (int i = 0; i < FM; ++i) {
            long rowb = row0 + wr * FM * 16 + i * 16 + quad * 4;
            #pragma unroll
            for (int j = 0; j < FN; ++j) {
                int col = col0 + wc * FN * 16 + j * 16 + l16;
                if (col < Ncol) {
                    #pragma unroll
                    for (int v = 0; v < 4; ++v) {
                        long r = rowb + v;
                        if (r < M) C[r * Ncol + col] = f2bf(acc[i][j][v]);
                    }
                }
            }
        }
    }
}

// Standalone GEMM kernel (layers 2 and 3).
template<int BN, int FM, int FN, bool CVT, bool FP8OUT, bool L4>
__global__ __launch_bounds__(512) void k_mfma(const void* __restrict__ Araw,
                                              const unsigned short* __restrict__ Bt,
                                              void* __restrict__ Cout,
                                              const float* __restrict__ a_s,
                                              const float* __restrict__ a_d,
                                              float* __restrict__ als,
                                              float* __restrict__ ald,
                                              int M, int K, int Ncol) {
    mfma_body<BN, FM, FN, CVT, FP8OUT, L4>(blockIdx.x, blockIdx.y,
                                           Araw, Bt, Cout, a_s, a_d, als, ald, M, K, Ncol);
}

// ---------------------------------------------------------------------------
// Front kernel: edge bucketing (blocks [0,256)) + ALL weight transposes
// ([256,704)).
// ---------------------------------------------------------------------------
__global__ __launch_bounds__(256) void k_front(const int* __restrict__ ei,
                                               int* __restrict__ fcur,
                                               unsigned int* __restrict__ fbuf,
                                               const float* __restrict__ W1,
                                               const float* __restrict__ W2,
                                               const float* __restrict__ W3,
                                               unsigned short* __restrict__ Wt1,
                                               unsigned short* __restrict__ Wt2,
                                               unsigned short* __restrict__ Wt3) {
    int b = blockIdx.x;
    if (b >= 256) {
        int i = (b - 256) * 256 + threadIdx.x;
        if (i < 32768) {                       // W1: 256 x 128
            int n = i >> 7, k = i & 127;
            Wt1[i] = f2bf(W1[(long)k * 256 + n]);
        } else if (i < 98304) {                // W2: 256 x 256
            int j = i - 32768;
            int n = j >> 8, k = j & 255;
            Wt2[j] = f2bf(W2[(long)k * 256 + n]);
        } else if (i < 114688) {               // W3: 64(pad) x 256
            int j = i - 98304;
            int n = j >> 8, k = j & 255;
            Wt3[j] = (n < OUT_CH) ? f2bf(W3[(long)k * OUT_CH + n]) : (unsigned short)0;
        }
        return;
    }
    // ---- edge bucketing ----
    __shared__ int lcnt[NFINE], lbase[NFINE], lcur[NFINE];
    int tid = threadIdx.x;
    for (int i = tid; i < NFINE; i += 256) lcnt[i] = 0;
    __syncthreads();
    for (int i = b * 256 + tid; i < ETOT; i += 256 * 256) {
        int d = (i < N_EDGES) ? ei[N_EDGES + i] : (i - N_EDGES);
        atomicAdd(&lcnt[d / NPF], 1);
    }
    __syncthreads();
    for (int i = tid; i < NFINE; i += 256) {
        lbase[i] = atomicAdd(&fcur[i], lcnt[i]);
        lcur[i] = 0;
    }
    __syncthreads();
    for (int i = b * 256 + tid; i < ETOT; i += 256 * 256) {
        int s, d;
        if (i < N_EDGES) { s = ei[i]; d = ei[N_EDGES + i]; }
        else             { s = i - N_EDGES; d = s; }
        int p = d / NPF;
        int off = atomicAdd(&lcur[p], 1);
        fbuf[(long)p * FCAP + lbase[p] + off] = (unsigned int)s | ((unsigned int)d << 16);
    }
}

// ---------------------------------------------------------------------------
// Mid kernel (512 threads): CSR finalize (blocks [0,512)) PARALLEL WITH the
// single-A-pass layer-1 GEMM ([512, 512+MBLK)).
// ---------------------------------------------------------------------------
__global__ __launch_bounds__(512) void k_mid(const int* __restrict__ fcur,
                                             const unsigned int* __restrict__ fbuf,
                                             int* __restrict__ deg,
                                             int* __restrict__ gcur,
                                             int* __restrict__ start,
                                             int* __restrict__ eSrc,
                                             const float* __restrict__ x,
                                             const unsigned short* __restrict__ Wt1,
                                             unsigned char* __restrict__ hA8,
                                             const float* __restrict__ as1,
                                             const float* __restrict__ ad1,
                                             float* __restrict__ als,
                                             float* __restrict__ ald) {
    int b = blockIdx.x;
    if (b >= NFINE) {
        mfma_body<256, 4, 4, true, true, true>(b - NFINE, 0,
                                               x, Wt1, hA8, as1, ad1, als, ald,
                                               N_NODES, IN_CH, 256);
        return;
    }
    // ---- CSR finalize: count + scan + global base + scatter + pad ----
    __shared__ int cnt[NPF];
    __shared__ int sval[128];
    __shared__ int offs[NPF];
    __shared__ int base_[NPF];
    __shared__ int pbase;
    int f = b;
    int tid = threadIdx.x;
    int n0 = f * NPF;
    int nend = min(n0 + NPF, N_NODES);
    int nn = nend - n0;
    if (tid < NPF) cnt[tid] = 0;
    __syncthreads();
    int n = fcur[f];
    for (int i = tid; i < n; i += 512)
        atomicAdd(&cnt[(int)(fbuf[(long)f * FCAP + i] >> 16) - n0], 1);
    __syncthreads();
    int pd = 0;
    if (tid < 128) {
        pd = (tid < nn) ? ((cnt[tid] + 7) & ~7) : 0;   // pad-8
        sval[tid] = pd;
    }
    __syncthreads();
    #pragma unroll
    for (int off = 1; off < 128; off <<= 1) {
        int t = 0;
        if (tid < 128 && tid >= off) t = sval[tid - off];
        __syncthreads();
        if (tid < 128) sval[tid] += t;
        __syncthreads();
    }
    if (tid == 0) pbase = atomicAdd(gcur, sval[127]);  // partition base, order-free
    __syncthreads();
    if (tid < nn) {
        int st = pbase + sval[tid] - pd;               // exclusive
        deg[n0 + tid] = cnt[tid];
        start[n0 + tid] = st;
        offs[tid] = st;
        base_[tid] = st;
    }
    __syncthreads();
    for (int i = tid; i < n; i += 512) {
        unsigned int u = fbuf[(long)f * FCAP + i];
        int d = (int)(u >> 16);
        int pos = atomicAdd(&offs[d - n0], 1);
        eSrc[pos] = (int)(u & 0xFFFFu);
    }
    __syncthreads();
    if (tid < nn) {
        int endp = offs[tid];
        int dg = endp - base_[tid];
        int stop = base_[tid] + ((dg + 7) & ~7);
        for (int k2 = endp; k2 < stop; ++k2) eSrc[k2] = -1;
    }
}

// ---------------------------------------------------------------------------
// Aggregation (4-head): quarter-wave per edge (16 lanes x uint4 = 256B/row),
// 16 ch/lane, split sbuf/wbuf LDS (conflict-free). At the L2-miss-serve floor
// (~44.5us) — three structures all pin here; do not restructure further.
// ---------------------------------------------------------------------------
__global__ __launch_bounds__(256) void k_agg4(const unsigned char* __restrict__ h8,
                                              const int* __restrict__ start,
                                              const int* __restrict__ deg,
                                              const int* __restrict__ eSrc,
                                              const float* __restrict__ als,
                                              const float* __restrict__ ald,
                                              const float* __restrict__ bias,
                                              unsigned short* __restrict__ out) {
    __shared__ float wbuf[4][CAP * 4];
    __shared__ int   sbuf[4][CAP];       // pre-scaled src byte offset (ss<<8)
    int wid = threadIdx.x >> 6;
    int node = (blockIdx.x * blockDim.x + threadIdx.x) >> 6;
    int lane = threadIdx.x & 63;
    if (node >= N_NODES) return;
    int st = start[node];
    int dgp = (deg[node] + 7) & ~7;
    const int* ep = eSrc + st;

    // ---- phase 1: weights into LDS ----
    int l16 = lane & 15, headw = lane >> 4;
    float aldd4 = ald[node * 4 + headw];
    int ncap = (dgp < CAP) ? dgp : CAP;
    for (int c = 0; c < ncap; c += 16) {
        int slot = c + l16;
        bool ok = (slot < ncap);
        int raw = ok ? ep[slot] : -1;
        int ss = (raw < 0) ? 0 : raw;
        float a = als[(long)ss * 4 + headw] + aldd4;
        float w = (raw < 0) ? 0.f : __expf(lrelu(a));
        if (ok) {
            wbuf[wid][slot * 4 + headw] = w;
            if (headw == 0) sbuf[wid][slot] = ss << 8;
        }
    }

    // ---- phase 2: quarter-wave per edge, 16 ch/lane (fp8 uint4) ----
    int q = lane >> 4;                   // quarter index = edge sub-slot
    int head = l16 >> 2;                 // 4 lanes per head
    const unsigned char* hb = h8 + l16 * 16;
    float den = 0.f;
    f32x2 acc2[8] = {};

    for (int j = 0; j < ncap; j += 8) {
        int  s0 = sbuf[wid][j + q];
        int  s1 = sbuf[wid][j + 4 + q];
        float w0 = wbuf[wid][(j + q) * 4 + head];
        float w1 = wbuf[wid][(j + 4 + q) * 4 + head];
        uint4 h0 = *(const uint4*)(hb + (long)s0);
        uint4 h1 = *(const uint4*)(hb + (long)s1);
        den += w0 + w1;
        f32x2 W0; W0.x = w0; W0.y = w0;
        f32x2 W1; W1.x = w1; W1.y = w1;
        acc2[0] += W0 * __builtin_amdgcn_cvt_pk_f32_fp8((int)h0.x, false);
        acc2[1] += W0 * __builtin_amdgcn_cvt_pk_f32_fp8((int)h0.x, true);
        acc2[2] += W0 * __builtin_amdgcn_cvt_pk_f32_fp8((int)h0.y, false);
        acc2[3] += W0 * __builtin_amdgcn_cvt_pk_f32_fp8((int)h0.y, true);
        acc2[4] += W0 * __builtin_amdgcn_cvt_pk_f32_fp8((int)h0.z, false);
        acc2[5] += W0 * __builtin_amdgcn_cvt_pk_f32_fp8((int)h0.z, true);
        acc2[6] += W0 * __builtin_amdgcn_cvt_pk_f32_fp8((int)h0.w, false);
        acc2[7] += W0 * __builtin_amdgcn_cvt_pk_f32_fp8((int)h0.w, true);
        acc2[0] += W1 * __builtin_amdgcn_cvt_pk_f32_fp8((int)h1.x, false);
        acc2[1] += W1 * __builtin_amdgcn_cvt_pk_f32_fp8((int)h1.x, true);
        acc2[2] += W1 * __builtin_amdgcn_cvt_pk_f32_fp8((int)h1.y, false);
        acc2[3] += W1 * __builtin_amdgcn_cvt_pk_f32_fp8((int)h1.y, true);
        acc2[4] += W1 * __builtin_amdgcn_cvt_pk_f32_fp8((int)h1.z, false);
        acc2[5] += W1 * __builtin_amdgcn_cvt_pk_f32_fp8((int)h1.z, true);
        acc2[6] += W1 * __builtin_amdgcn_cvt_pk_f32_fp8((int)h1.w, false);
        acc2[7] += W1 * __builtin_amdgcn_cvt_pk_f32_fp8((int)h1.w, true);
    }

    if (dgp > ncap) {                    // overflow (deg > 64: ~never)
        float alddq = ald[node * 4 + head];
        for (int j = ncap; j < dgp; j += 4) {
            int raw = ep[j + q];
            int ss = (raw < 0) ? 0 : raw;
            float w = (raw < 0) ? 0.f : __expf(lrelu(als[(long)ss * 4 + head] + alddq));
            uint4 hv = *(const uint4*)(h8 + ((long)ss << 8) + l16 * 16);
            den += w;
            f32x2 W0; W0.x = w; W0.y = w;
            acc2[0] += W0 * __builtin_amdgcn_cvt_pk_f32_fp8((int)hv.x, false);
            acc2[1] += W0 * __builtin_amdgcn_cvt_pk_f32_fp8((int)hv.x, true);
            acc2[2] += W0 * __builtin_amdgcn_cvt_pk_f32_fp8((int)hv.y, false);
            acc2[3] += W0 * __builtin_amdgcn_cvt_pk_f32_fp8((int)hv.y, true);
            acc2[4] += W0 * __builtin_amdgcn_cvt_pk_f32_fp8((int)hv.z, false);
            acc2[5] += W0 * __builtin_amdgcn_cvt_pk_f32_fp8((int)hv.z, true);
            acc2[6] += W0 * __builtin_amdgcn_cvt_pk_f32_fp8((int)hv.w, false);
            acc2[7] += W0 * __builtin_amdgcn_cvt_pk_f32_fp8((int)hv.w, true);
        }
    }

    // reduce across the 4 quarters (lanes with equal l16)
    den += __shfl_xor(den, 16);
    den += __shfl_xor(den, 32);
    #pragma unroll
    for (int c = 0; c < 8; ++c) {
        acc2[c].x += __shfl_xor(acc2[c].x, 16);
        acc2[c].y += __shfl_xor(acc2[c].y, 16);
        acc2[c].x += __shfl_xor(acc2[c].x, 32);
        acc2[c].y += __shfl_xor(acc2[c].y, 32);
    }

    if (q == 0) {
        float inv = 1.f / den;
        int cb = l16 * 16;
        float4 b0 = *(const float4*)(bias + cb);
        float4 b1 = *(const float4*)(bias + cb + 4);
        float4 b2 = *(const float4*)(bias + cb + 8);
        float4 b3 = *(const float4*)(bias + cb + 12);
        float v0  = fmaxf(acc2[0].x * inv + b0.x, 0.f);
        float v1  = fmaxf(acc2[0].y * inv + b0.y, 0.f);
        float v2  = fmaxf(acc2[1].x * inv + b0.z, 0.f);
        float v3  = fmaxf(acc2[1].y * inv + b0.w, 0.f);
        float v4  = fmaxf(acc2[2].x * inv + b1.x, 0.f);
        float v5  = fmaxf(acc2[2].y * inv + b1.y, 0.f);
        float v6  = fmaxf(acc2[3].x * inv + b1.z, 0.f);
        float v7  = fmaxf(acc2[3].y * inv + b1.w, 0.f);
        float v8  = fmaxf(acc2[4].x * inv + b2.x, 0.f);
        float v9  = fmaxf(acc2[4].y * inv + b2.y, 0.f);
        float v10 = fmaxf(acc2[5].x * inv + b2.z, 0.f);
        float v11 = fmaxf(acc2[5].y * inv + b2.w, 0.f);
        float v12 = fmaxf(acc2[6].x * inv + b3.x, 0.f);
        float v13 = fmaxf(acc2[6].y * inv + b3.y, 0.f);
        float v14 = fmaxf(acc2[7].x * inv + b3.z, 0.f);
        float v15 = fmaxf(acc2[7].y * inv + b3.w, 0.f);
        uint4 o0, o1;
        o0.x = (unsigned int)f2bf(v0)  | ((unsigned int)f2bf(v1)  << 16);
        o0.y = (unsigned int)f2bf(v2)  | ((unsigned int)f2bf(v3)  << 16);
        o0.z = (unsigned int)f2bf(v4)  | ((unsigned int)f2bf(v5)  << 16);
        o0.w = (unsigned int)f2bf(v6)  | ((unsigned int)f2bf(v7)  << 16);
        o1.x = (unsigned int)f2bf(v8)  | ((unsigned int)f2bf(v9)  << 16);
        o1.y = (unsigned int)f2bf(v10) | ((unsigned int)f2bf(v11) << 16);
        o1.z = (unsigned int)f2bf(v12) | ((unsigned int)f2bf(v13) << 16);
        o1.w = (unsigned int)f2bf(v14) | ((unsigned int)f2bf(v15) << 16);
        *(uint4*)(out + (long)node * 256 + cb) = o0;
        *(uint4*)(out + (long)node * 256 + cb + 8) = o1;
    }
}

// ---------------------------------------------------------------------------
// Final layer agg (exact proven R14 version, pad-8).
// ---------------------------------------------------------------------------
__global__ __launch_bounds__(256) void k_agg1(const unsigned short* __restrict__ h,
                                              const int* __restrict__ start,
                                              const int* __restrict__ deg,
                                              const int* __restrict__ eSrc,
                                              const float* __restrict__ als,
                                              const float* __restrict__ ald,
                                              const float* __restrict__ bias,
                                              float* __restrict__ out) {
    int node = (blockIdx.x * blockDim.x + threadIdx.x) >> 6;
    int lane = threadIdx.x & 63;
    if (node >= N_NODES) return;
    int q = lane >> 4, r = lane & 15;
    bool act = (r < 10);
    int st = start[node];
    int dgp = (deg[node] + 7) & ~7;
    const int* ep = eSrc + st;
    float aldd = ald[node];

    float den = 0.f;
    float4 acc = {0.f, 0.f, 0.f, 0.f};

    int j = 0;
    for (; j + 16 <= dgp; j += 16) {
        int base = j + q * 4;
        int s[4];
        float w[4];
        #pragma unroll
        for (int u = 0; u < 4; ++u) s[u] = ep[base + u];
        #pragma unroll
        for (int u = 0; u < 4; ++u) {
            int raw = s[u];
            int ss = (raw < 0) ? 0 : raw;
            w[u] = (raw < 0) ? 0.f : __expf(lrelu(als[ss] + aldd));
            s[u] = ss;
        }
        ushort4 hh[4];
        #pragma unroll
        for (int u = 0; u < 4; ++u) {
            ushort4 t = {0, 0, 0, 0};
            if (act) t = *(const ushort4*)(h + (long)s[u] * OUT_CH + r * 4);
            hh[u] = t;
        }
        #pragma unroll
        for (int u = 0; u < 4; ++u) {
            den += w[u];
            acc.x += w[u] * bf2f(hh[u].x);
            acc.y += w[u] * bf2f(hh[u].y);
            acc.z += w[u] * bf2f(hh[u].z);
            acc.w += w[u] * bf2f(hh[u].w);
        }
    }
    if (j < dgp) {
        int base = j + q * 2;
        int s[2];
        float w[2];
        #pragma unroll
        for (int u = 0; u < 2; ++u) s[u] = ep[base + u];
        #pragma unroll
        for (int u = 0; u < 2; ++u) {
            int raw = s[u];
            int ss = (raw < 0) ? 0 : raw;
            w[u] = (raw < 0) ? 0.f : __expf(lrelu(als[ss] + aldd));
            s[u] = ss;
        }
        ushort4 hh[2];
        #pragma unroll
        for (int u = 0; u < 2; ++u) {
            ushort4 t = {0, 0, 0, 0};
            if (act) t = *(const ushort4*)(h + (long)s[u] * OUT_CH + r * 4);
            hh[u] = t;
        }
        #pragma unroll
        for (int u = 0; u < 2; ++u) {
            den += w[u];
            acc.x += w[u] * bf2f(hh[u].x);
            acc.y += w[u] * bf2f(hh[u].y);
            acc.z += w[u] * bf2f(hh[u].z);
            acc.w += w[u] * bf2f(hh[u].w);
        }
    }

    #pragma unroll
    for (int off = 16; off < 64; off <<= 1) {
        acc.x += __shfl_xor(acc.x, off);
        acc.y += __shfl_xor(acc.y, off);
        acc.z += __shfl_xor(acc.z, off);
        acc.w += __shfl_xor(acc.w, off);
        den   += __shfl_xor(den, off);
    }
    float inv = 1.f / den;
    float4 bv = {0.f, 0.f, 0.f, 0.f};
    if (act) bv = *(const float4*)(bias + r * 4);
    float4 v;
    v.x = acc.x * inv + bv.x;
    v.y = acc.y * inv + bv.y;
    v.z = acc.z * inv + bv.z;
    v.w = acc.w * inv + bv.w;
    float mx = act ? fmaxf(fmaxf(v.x, v.y), fmaxf(v.z, v.w)) : -INFINITY;
    #pragma unroll
    for (int off = 1; off < 16; off <<= 1) mx = fmaxf(mx, __shfl_xor(mx, off));
    float sum = act ? (__expf(v.x - mx) + __expf(v.y - mx) + __expf(v.z - mx) + __expf(v.w - mx)) : 0.f;
    #pragma unroll
    for (int off = 1; off < 16; off <<= 1) sum += __shfl_xor(sum, off);
    float lse = mx + logf(sum);
    if (q == 0 && act) {
        float4 o;
        o.x = v.x - lse;
        o.y = v.y - lse;
        o.z = v.z - lse;
        o.w = v.w - lse;
        *(float4*)(out + (long)node * OUT_CH + r * 4) = o;
    }
}

// ---------------------------------------------------------------------------
extern "C" void kernel_launch(void* const* d_in, const int* in_sizes, int n_in,
                              void* d_out, int out_size, void* d_ws, size_t ws_size,
                              hipStream_t stream) {
    (void)in_sizes; (void)n_in; (void)out_size; (void)ws_size;
    const float* x   = (const float*)d_in[0];
    const int*   ei  = (const int*)d_in[1];
    const float* W1  = (const float*)d_in[2];
    const float* as1 = (const float*)d_in[3];
    const float* ad1 = (const float*)d_in[4];
    const float* b1  = (const float*)d_in[5];
    const float* W2  = (const float*)d_in[6];
    const float* as2 = (const float*)d_in[7];
    const float* ad2 = (const float*)d_in[8];
    const float* b2  = (const float*)d_in[9];
    const float* W3  = (const float*)d_in[10];
    const float* as3 = (const float*)d_in[11];
    const float* ad3 = (const float*)d_in[12];
    const float* b3  = (const float*)d_in[13];
    float* out = (float*)d_out;

    char* p = (char*)d_ws;
    auto alloc = [&](size_t b) { char* r = p; p += (b + 255) & ~(size_t)255; return r; };
    int*   deg   = (int*)alloc((size_t)N_NODES * 4);
    int*   start = (int*)alloc((size_t)N_NODES * 4);
    int*   psum  = (int*)alloc((size_t)NFINE * 4);   // psum[0] = global cursor
    int*   fcur  = (int*)alloc((size_t)NFINE * 4);   // adjacent to psum (both 2048B, 256-aligned)
    unsigned int* fbuf = (unsigned int*)alloc((size_t)NFINE * FCAP * 4);
    int*   eSrc  = (int*)alloc((size_t)EPAD_MAX * 4);
    float* als   = (float*)alloc((size_t)N_NODES * 4 * 4);
    float* ald   = (float*)alloc((size_t)N_NODES * 4 * 4);
    unsigned char*  hA8  = (unsigned char*)alloc((size_t)N_NODES * 256);
    unsigned short* hBbf = (unsigned short*)alloc((size_t)N_NODES * 256 * 2);
    unsigned short* h3bf = (unsigned short*)alloc((size_t)N_NODES * OUT_CH * 2);
    unsigned short* Wt1  = (unsigned short*)alloc((size_t)256 * IN_CH * 2);
    unsigned short* Wt2  = (unsigned short*)alloc((size_t)256 * 256 * 2);
    unsigned short* Wt3  = (unsigned short*)alloc((size_t)64 * 256 * 2);

    const int WB = (N_NODES + 3) / 4;

    // ---- front: memset, then {bucketing || all transposes} ----
    hipMemsetAsync(psum, 0, (size_t)NFINE * 8, stream);
    k_front<<<704, 256, 0, stream>>>(ei, fcur, fbuf, W1, W2, W3, Wt1, Wt2, Wt3);

    // ---- mid: {CSR finalize || single-pass layer-1 GEMM} ----
    k_mid<<<NFINE + MBLK, 512, 0, stream>>>(fcur, fbuf, deg, psum, start, eSrc,
                                            x, Wt1, hA8, as1, ad1, als, ald);

    // ---- layer 1 aggregation ----
    k_agg4<<<WB, 256, 0, stream>>>(hA8, start, deg, eSrc, als, ald, b1, hBbf);

    // ---- layer 2 (bf16 in, fp8 out, fused logits, single-A-pass) ----
    k_mfma<256, 4, 4, false, true, true><<<dim3(MBLK, 1), 512, 0, stream>>>(
        hBbf, Wt2, hA8, as2, ad2, als, ald, N_NODES, 256, 256);
    k_agg4<<<WB, 256, 0, stream>>>(hA8, start, deg, eSrc, als, ald, b2, hBbf);

    // ---- layer 3 (bf16 in, bf16 out, fused single-head logits) ----
    k_mfma<64, 2, 4, false, false, false><<<dim3(MBLK, 1), 256, 0, stream>>>(
        hBbf, Wt3, h3bf, as3, ad3, als, ald, N_NODES, 256, OUT_CH);
    k_agg1<<<WB, 256, 0, stream>>>(h3bf, start, deg, eSrc, als, ald, b3, out);
}